// Round 19
// baseline (226.123 us; speedup 1.0000x reference)
//
#include <hip/hip_runtime.h>
#include <hip/hip_bf16.h>
#include <cstdint>
#include <cstddef>

typedef __attribute__((ext_vector_type(8))) short bf16x8;
typedef __attribute__((ext_vector_type(8))) unsigned short ushort8;
typedef __attribute__((ext_vector_type(4))) unsigned short ushort4v;
typedef __attribute__((ext_vector_type(4))) float f32x4;

#define B_ 8
#define S_ 1024
#define E_ 1024
#define H_ 16
#define D_ 64
#define NW_ (S_ / 64)  // mask words per row

__device__ __forceinline__ unsigned short f2bf(float f) {
    union { float fp; unsigned int u; } v; v.fp = f;
    unsigned int u = v.u;
    return (unsigned short)((u + 0x7fffu + ((u >> 16) & 1u)) >> 16);
}

__device__ __forceinline__ float fexp2(float x) {
    return __builtin_amdgcn_exp2f(x);  // v_exp_f32: D = 2^S0
}

__device__ __forceinline__ unsigned cvt_pk_bf16(float lo, float hi) {
    unsigned r;
    asm("v_cvt_pk_bf16_f32 %0, %1, %2" : "=v"(r) : "v"(lo), "v"(hi));
    return r;
}

__device__ __forceinline__ void gload16(const void* g, void* l) {
    __builtin_amdgcn_global_load_lds((__attribute__((address_space(1))) void*)g,
                                     (__attribute__((address_space(3))) void*)l,
                                     16, 0, 0);
}

// ---------------- f32 -> bf16 bulk convert (single) -------------------------
__global__ __launch_bounds__(256) void f32_to_bf16(const float* __restrict__ in,
                                                   unsigned short* __restrict__ out,
                                                   int n8) {
    int i = blockIdx.x * 256 + threadIdx.x;
    const int stride = gridDim.x * 256;
    for (; i < n8; i += stride) {
        float4 f0 = ((const float4*)in)[i * 2];
        float4 f1 = ((const float4*)in)[i * 2 + 1];
        union { unsigned u[4]; ushort8 v; } o;
        o.u[0] = cvt_pk_bf16(f0.x, f0.y);
        o.u[1] = cvt_pk_bf16(f0.z, f0.w);
        o.u[2] = cvt_pk_bf16(f1.x, f1.y);
        o.u[3] = cvt_pk_bf16(f1.z, f1.w);
        ((ushort8*)out)[i] = o.v;
    }
}

// ---------------- f32 -> bf16 bulk convert (3 tensors, one dispatch) --------
__global__ __launch_bounds__(256) void cvt3(const float* __restrict__ i0,
                                            const float* __restrict__ i1,
                                            const float* __restrict__ i2,
                                            unsigned short* __restrict__ o0,
                                            unsigned short* __restrict__ o1,
                                            unsigned short* __restrict__ o2,
                                            int n8) {
    const float* in = (blockIdx.z == 0) ? i0 : (blockIdx.z == 1) ? i1 : i2;
    unsigned short* out = (blockIdx.z == 0) ? o0 : (blockIdx.z == 1) ? o1 : o2;
    int i = blockIdx.x * 256 + threadIdx.x;
    const int stride = gridDim.x * 256;
    for (; i < n8; i += stride) {
        float4 f0 = ((const float4*)in)[i * 2];
        float4 f1 = ((const float4*)in)[i * 2 + 1];
        union { unsigned u[4]; ushort8 v; } o;
        o.u[0] = cvt_pk_bf16(f0.x, f0.y);
        o.u[1] = cvt_pk_bf16(f0.z, f0.w);
        o.u[2] = cvt_pk_bf16(f1.x, f1.y);
        o.u[3] = cvt_pk_bf16(f1.z, f1.w);
        ((ushort8*)out)[i] = o.v;
    }
}

// ---------------- weight transpose-convert: 4 × (W[K][N] f32 -> Wt[N][K]) ---
__global__ __launch_bounds__(256) void wtrans4(const float* __restrict__ W0,
                                               const float* __restrict__ W1,
                                               const float* __restrict__ W2,
                                               const float* __restrict__ W3,
                                               unsigned short* __restrict__ T0,
                                               unsigned short* __restrict__ T1,
                                               unsigned short* __restrict__ T2,
                                               unsigned short* __restrict__ T3) {
    const float* W = (blockIdx.z == 0) ? W0 : (blockIdx.z == 1) ? W1 : (blockIdx.z == 2) ? W2 : W3;
    unsigned short* Wt = (blockIdx.z == 0) ? T0 : (blockIdx.z == 1) ? T1 : (blockIdx.z == 2) ? T2 : T3;
    __shared__ float tile[32][33];
    const int k0 = blockIdx.y * 32, n0 = blockIdx.x * 32;
    const int tx = threadIdx.x & 31, ty = threadIdx.x >> 5;
#pragma unroll
    for (int i = ty; i < 32; i += 8)
        tile[i][tx] = W[(size_t)(k0 + i) * E_ + n0 + tx];
    __syncthreads();
#pragma unroll
    for (int i = ty; i < 32; i += 8)
        Wt[(size_t)(n0 + i) * E_ + k0 + tx] = f2bf(tile[tx][i]);
}

// ---------------- mask bit-pack with inline dtype detection -----------------
__global__ __launch_bounds__(256) void pack_mask(const void* __restrict__ maskp,
                                                 unsigned long long* __restrict__ mbits) {
    const unsigned int* m32h = (const unsigned int*)maskp;
    unsigned int bad = 0;
    for (int i = threadIdx.x; i < 4096; i += 256) bad |= (m32h[i] > 1u) ? 1u : 0u;
    __shared__ int s_is32;
    if (threadIdx.x == 0) s_is32 = 1;
    __syncthreads();
    if (bad) s_is32 = 0;
    __syncthreads();
    const int mask32 = s_is32;

    const int lane = threadIdx.x & 63;
    const int gw = blockIdx.x * 4 + (threadIdx.x >> 6);
    const int nwaves = gridDim.x * 4;
    const int totw = B_ * S_ * NW_;
    for (int w = gw; w < totw; w += nwaves) {
        bool m;
        if (mask32) m = ((const int*)maskp)[(size_t)w * 64 + lane] != 0;
        else        m = ((const unsigned char*)maskp)[(size_t)w * 64 + lane] != 0;
        unsigned long long bits = __ballot(m);
        if (lane == 0) mbits[w] = bits;
    }
}

// ---------------- GEMM (BK=64 + rule-21 swizzle, single buffer) -------------
// EPI 0: bf16 [B,H,S,D] (scaled); EPI 2: bf16 [B,H,D,S]; EPI 3: f32+resid.
template <int EPI>
__global__ __launch_bounds__(256) void gemm_bt(const unsigned short* __restrict__ A,
                                               const unsigned short* __restrict__ Bt,
                                               void* __restrict__ Cp,
                                               const float* __restrict__ resid,
                                               float cscale) {
    __shared__ unsigned short As[128 * 64];  // 16 KB
    __shared__ unsigned short Bs[128 * 64];  // 16 KB
    const int t = threadIdx.x;
    const int lane = t & 63, w = t >> 6;
    const int wr = w >> 1, wc = w & 1;
    const int l15 = lane & 15, l4 = lane >> 4;
    const int m0 = blockIdx.x * 128, n0 = blockIdx.y * 128;

    const int lr = lane >> 3, lc = lane & 7;
    const int csrc = (lc ^ lr) * 8;  // inverse-swizzled source col (shorts)
    const unsigned short* Ag[4];
    const unsigned short* Bg[4];
#pragma unroll
    for (int g = 0; g < 4; ++g) {
        Ag[g] = A + (size_t)(m0 + w * 32 + g * 8 + lr) * E_ + csrc;
        Bg[g] = Bt + (size_t)(n0 + w * 32 + g * 8 + lr) * E_ + csrc;
    }
    unsigned short* Al = &As[w * 32 * 64];
    unsigned short* Bl = &Bs[w * 32 * 64];

    f32x4 acc[4][4];
#pragma unroll
    for (int i = 0; i < 4; ++i)
#pragma unroll
        for (int j = 0; j < 4; ++j) acc[i][j] = (f32x4){0.f, 0.f, 0.f, 0.f};

    const int r7 = (l15 & 7) << 4;  // (row&7)*16 bytes
    const char* AsB = (const char*)As;
    const char* BsB = (const char*)Bs;

    for (int kt = 0; kt < E_; kt += 64) {
#pragma unroll
        for (int g = 0; g < 4; ++g) {
            gload16(Ag[g] + kt, Al + g * 512);
            gload16(Bg[g] + kt, Bl + g * 512);
        }
        __syncthreads();
#pragma unroll
        for (int kk = 0; kk < 2; ++kk) {
            bf16x8 af[4], bfv[4];
#pragma unroll
            for (int mi = 0; mi < 4; ++mi)
                af[mi] = *(const bf16x8*)(AsB + (size_t)(wr * 64 + mi * 16 + l15) * 128 +
                                          ((((kk * 4 + l4) << 4)) ^ r7));
#pragma unroll
            for (int ni = 0; ni < 4; ++ni)
                bfv[ni] = *(const bf16x8*)(BsB + (size_t)(wc * 64 + ni * 16 + l15) * 128 +
                                           ((((kk * 4 + l4) << 4)) ^ r7));
#pragma unroll
            for (int mi = 0; mi < 4; ++mi)
#pragma unroll
                for (int ni = 0; ni < 4; ++ni)
                    acc[mi][ni] = __builtin_amdgcn_mfma_f32_16x16x32_bf16(af[mi], bfv[ni],
                                                                          acc[mi][ni], 0, 0, 0);
        }
        __syncthreads();
    }
#pragma unroll
    for (int mi = 0; mi < 4; ++mi) {
#pragma unroll
        for (int ni = 0; ni < 4; ++ni) {
#pragma unroll
            for (int r = 0; r < 4; ++r) {
                const int m = m0 + wr * 64 + mi * 16 + l4 * 4 + r;
                const int n = n0 + wc * 64 + ni * 16 + l15;
                const float v = acc[mi][ni][r];
                if (EPI == 0) {
                    const int b = m >> 10, s = m & 1023, h = n >> 6, d = n & 63;
                    ((unsigned short*)Cp)[(((size_t)b * H_ + h) * S_ + s) * D_ + d] = f2bf(v * cscale);
                } else if (EPI == 2) {
                    const int b = m >> 10, s = m & 1023, h = n >> 6, d = n & 63;
                    ((unsigned short*)Cp)[(((size_t)b * H_ + h) * D_ + d) * S_ + s] = f2bf(v);
                } else {
                    const size_t idx = (size_t)m * E_ + n;
                    ((float*)Cp)[idx] = v + resid[idx];
                }
            }
        }
    }
}

// ---------------- flash attention (8 waves, dbuf K/V via global_load_lds) ---
__global__ __launch_bounds__(512) void attn_kernel(const unsigned short* __restrict__ Qh,
                                                   const unsigned short* __restrict__ Kh,
                                                   const unsigned short* __restrict__ Vt,
                                                   const unsigned long long* __restrict__ mbits,
                                                   unsigned short* __restrict__ degree) {
    __shared__ unsigned short Ks[2][64 * 64];   // 16 KB
    __shared__ unsigned short Vs[2][64 * 64];   // 16 KB
    __shared__ unsigned short Ps[8 * 16 * 64];  // 16 KB (per-wave 16x64)
    const int t = threadIdx.x;
    const int lane = t & 63, w = t >> 6;  // w 0..7
    const int l15 = lane & 15, l4 = lane >> 4;
    const int i = blockIdx.x;
    const int L = (i & 7) * 128 + (i >> 3);  // bijective, nwg=1024
    const int bh = L >> 3, b = bh >> 4, h = bh & 15;
    const int q0 = (L & 7) * 128;
    const int myq = q0 + w * 16 + l15;

    const unsigned long long* mrow = mbits + ((size_t)b * S_ + myq) * NW_;

    bf16x8 qf[2];
    {
        const unsigned short* qptr = Qh + ((size_t)bh * S_ + myq) * D_ + l4 * 8;
        qf[0] = *(const bf16x8*)qptr;
        qf[1] = *(const bf16x8*)(qptr + 32);
    }
    f32x4 O[4];
#pragma unroll
    for (int idx = 0; idx < 4; ++idx) O[idx] = (f32x4){0.f, 0.f, 0.f, 0.f};
    float mrun = -3e38f, lrun = 0.f;

    const int srow = t >> 3, slot = t & 7;
    const int scs = (slot ^ (srow & 7)) * 8;  // rule-21 inverse swizzle source
    const unsigned short* kgb = Kh + ((size_t)bh * S_ + srow) * D_ + scs;
    const unsigned short* vgb = Vt + ((size_t)bh * D_ + srow) * S_ + scs;

    char* PsB = (char*)Ps + w * 2048;
    const int psw = (l15 & 7) << 4;

    gload16(kgb, &Ks[0][w * 512]);
    gload16(vgb, &Vs[0][w * 512]);

    int cur = 0;
    for (int jt = 0; jt < S_; jt += 64) {
        __syncthreads();
        if (jt + 64 < S_) {
            gload16(kgb + (size_t)(jt + 64) * D_, &Ks[cur ^ 1][w * 512]);
            gload16(vgb + (jt + 64), &Vs[cur ^ 1][w * 512]);
        }
        const unsigned long long mw = mrow[jt >> 6];
        const char* KsB = (const char*)Ks[cur];
        const char* VsB = (const char*)Vs[cur];

        f32x4 sacc[4];
#pragma unroll
        for (int idx = 0; idx < 4; ++idx) sacc[idx] = (f32x4){0.f, 0.f, 0.f, 0.f};
#pragma unroll
        for (int ni = 0; ni < 4; ++ni) {
            const int row = l15 + ni * 16;
            const int sw = (row & 7) << 4;
            bf16x8 b0 = *(const bf16x8*)(KsB + row * 128 + ((l4 * 16) ^ sw));
            bf16x8 b1 = *(const bf16x8*)(KsB + row * 128 + ((64 + l4 * 16) ^ sw));
            sacc[ni] = __builtin_amdgcn_mfma_f32_16x16x32_bf16(b0, qf[0], sacc[ni], 0, 0, 0);
            sacc[ni] = __builtin_amdgcn_mfma_f32_16x16x32_bf16(b1, qf[1], sacc[ni], 0, 0, 0);
        }

        float m0 = -3e38f;
#pragma unroll
        for (int ni = 0; ni < 4; ++ni) {
#pragma unroll
            for (int r = 0; r < 4; ++r) {
                const int k = ni * 16 + l4 * 4 + r;
                const float s = ((mw >> k) & 1ull) ? -1e9f : sacc[ni][r];
                sacc[ni][r] = s;
                m0 = fmaxf(m0, s);
            }
        }
        m0 = fmaxf(m0, __shfl_xor(m0, 16, 64));
        m0 = fmaxf(m0, __shfl_xor(m0, 32, 64));
        if (!__all(m0 <= mrun + 8.f)) {
            const float mnew = fmaxf(mrun, m0);
            const float corr = fexp2(mrun - mnew);
            lrun *= corr;
#pragma unroll
            for (int df = 0; df < 4; ++df)
#pragma unroll
                for (int r = 0; r < 4; ++r) O[df][r] *= corr;
            mrun = mnew;
        }
        float ps = 0.f;
#pragma unroll
        for (int ni = 0; ni < 4; ++ni) {
            float p0 = fexp2(sacc[ni][0] - mrun);
            float p1 = fexp2(sacc[ni][1] - mrun);
            float p2 = fexp2(sacc[ni][2] - mrun);
            float p3 = fexp2(sacc[ni][3] - mrun);
            ps += (p0 + p1) + (p2 + p3);
            uint2 pw;
            pw.x = cvt_pk_bf16(p0, p1);
            pw.y = cvt_pk_bf16(p2, p3);
            *(uint2*)(PsB + l15 * 128 + ((ni * 32 + l4 * 8) ^ psw)) = pw;
        }
        ps += __shfl_xor(ps, 16, 64);
        ps += __shfl_xor(ps, 32, 64);
        lrun += ps;

        asm volatile("s_waitcnt lgkmcnt(0)" ::: "memory");
        bf16x8 pa0 = *(const bf16x8*)(PsB + l15 * 128 + ((l4 * 16) ^ psw));
        bf16x8 pa1 = *(const bf16x8*)(PsB + l15 * 128 + ((64 + l4 * 16) ^ psw));
#pragma unroll
        for (int df = 0; df < 4; ++df) {
            const int row = l15 + df * 16;
            const int sw = (row & 7) << 4;
            bf16x8 v0 = *(const bf16x8*)(VsB + row * 128 + ((l4 * 16) ^ sw));
            bf16x8 v1 = *(const bf16x8*)(VsB + row * 128 + ((64 + l4 * 16) ^ sw));
            O[df] = __builtin_amdgcn_mfma_f32_16x16x32_bf16(v0, pa0, O[df], 0, 0, 0);
            O[df] = __builtin_amdgcn_mfma_f32_16x16x32_bf16(v1, pa1, O[df], 0, 0, 0);
        }
        cur ^= 1;
    }

    const float inv = 1.f / lrun;
#pragma unroll
    for (int df = 0; df < 4; ++df) {
        ushort4v ow;
#pragma unroll
        for (int r = 0; r < 4; ++r) ow[r] = f2bf(O[df][r] * inv);
        const size_t dst = ((size_t)b * S_ + myq) * (size_t)(H_ * D_) +
                           h * 64 + df * 16 + l4 * 4;
        *(ushort4v*)(degree + dst) = ow;
    }
}

// ---------------- in-place row LayerNorm over E=1024 ------------------------
__global__ __launch_bounds__(256) void lnorm(float* __restrict__ io,
                                             const float* __restrict__ gamma,
                                             const float* __restrict__ beta) {
    const int row = blockIdx.x;
    const int t = threadIdx.x;
    float4 v = ((const float4*)(io + (size_t)row * E_))[t];
    float s = v.x + v.y + v.z + v.w;
    float q = v.x * v.x + v.y * v.y + v.z * v.z + v.w * v.w;
#pragma unroll
    for (int off = 32; off; off >>= 1) {
        s += __shfl_down(s, off, 64);
        q += __shfl_down(q, off, 64);
    }
    __shared__ float red[8];
    const int wid = t >> 6;
    if ((t & 63) == 0) { red[wid] = s; red[4 + wid] = q; }
    __syncthreads();
    const float ts = red[0] + red[1] + red[2] + red[3];
    const float tq = red[4] + red[5] + red[6] + red[7];
    const float mean = ts * (1.0f / E_);
    const float var = tq * (1.0f / E_) - mean * mean;
    const float rstd = rsqrtf(var + 1e-5f);
    const float4 g = ((const float4*)gamma)[t];
    const float4 bb = ((const float4*)beta)[t];
    v.x = (v.x - mean) * rstd * g.x + bb.x;
    v.y = (v.y - mean) * rstd * g.y + bb.y;
    v.z = (v.z - mean) * rstd * g.z + bb.z;
    v.w = (v.w - mean) * rstd * g.w + bb.w;
    ((float4*)(io + (size_t)row * E_))[t] = v;
}

extern "C" void kernel_launch(void* const* d_in, const int* in_sizes, int n_in,
                              void* d_out, int out_size, void* d_ws, size_t ws_size,
                              hipStream_t stream) {
    const float* query = (const float*)d_in[0];
    const float* key_ = (const float*)d_in[1];
    const float* value = (const float*)d_in[2];
    const void* maskp = d_in[3];
    const float* Wq = (const float*)d_in[4];
    const float* Wk = (const float*)d_in[5];
    const float* Wv = (const float*)d_in[6];
    const float* Wo = (const float*)d_in[7];
    const float* gamma = (const float*)d_in[8];
    const float* beta = (const float*)d_in[9];
    float* out = (float*)d_out;
    char* ws = (char*)d_ws;
    const size_t MB = 1024ull * 1024ull;

    unsigned short* WqT = (unsigned short*)(ws + 0 * MB);
    unsigned short* WkT = (unsigned short*)(ws + 2 * MB);
    unsigned short* WvT = (unsigned short*)(ws + 4 * MB);
    unsigned short* WoT = (unsigned short*)(ws + 6 * MB);
    unsigned short* Qh = (unsigned short*)(ws + 8 * MB);   // [B,H,S,D] bf16
    unsigned short* Kh = (unsigned short*)(ws + 24 * MB);  // [B,H,S,D] bf16
    unsigned short* Vt = (unsigned short*)(ws + 40 * MB);  // [B,H,D,S] bf16
    unsigned short* deg = (unsigned short*)(ws + 56 * MB); // [B,S,H*D] bf16
    unsigned long long* mbits = (unsigned long long*)(ws + 72 * MB + 4096);

    const int n8 = B_ * S_ * E_ / 8;
    const float qscale = 0.125f * 1.4426950408889634f;  // 1/sqrt(D) * log2(e)

    wtrans4<<<dim3(32, 32, 4), 256, 0, stream>>>(Wq, Wk, Wv, Wo, WqT, WkT, WvT, WoT);
    pack_mask<<<2048, 256, 0, stream>>>(maskp, mbits);

    if (ws_size >= 108 * MB) {
        // one convert dispatch into 3 disjoint bf16 buffers, then 3 GEMMs
        unsigned short* A0 = deg;                              // 56-72 MB
        unsigned short* A1 = (unsigned short*)(ws + 74 * MB);  // 74-90 MB
        unsigned short* A2 = (unsigned short*)(ws + 90 * MB);  // 90-106 MB
        cvt3<<<dim3(1024, 1, 3), 256, 0, stream>>>(query, key_, value, A0, A1, A2, n8);
        gemm_bt<0><<<dim3(64, 8), 256, 0, stream>>>(A0, WqT, Qh, nullptr, qscale);
        gemm_bt<0><<<dim3(64, 8), 256, 0, stream>>>(A1, WkT, Kh, nullptr, 1.0f);
        gemm_bt<2><<<dim3(64, 8), 256, 0, stream>>>(A2, WvT, Vt, nullptr, 1.0f);
    } else {
        // sequential fallback (single shared A buffer in deg)
        unsigned short* Abf = deg;
        f32_to_bf16<<<2048, 256, 0, stream>>>(query, Abf, n8);
        gemm_bt<0><<<dim3(64, 8), 256, 0, stream>>>(Abf, WqT, Qh, nullptr, qscale);
        f32_to_bf16<<<2048, 256, 0, stream>>>(key_, Abf, n8);
        gemm_bt<0><<<dim3(64, 8), 256, 0, stream>>>(Abf, WkT, Kh, nullptr, 1.0f);
        f32_to_bf16<<<2048, 256, 0, stream>>>(value, Abf, n8);
        gemm_bt<2><<<dim3(64, 8), 256, 0, stream>>>(Abf, WvT, Vt, nullptr, 1.0f);
    }

    attn_kernel<<<1024, 512, 0, stream>>>(Qh, Kh, Vt, mbits, deg);

    gemm_bt<3><<<dim3(64, 8), 256, 0, stream>>>(deg, WoT, out, query, 1.0f);
    lnorm<<<8192, 256, 0, stream>>>(out, gamma, beta);
}

// Round 20
// 218.310 us; speedup vs baseline: 1.0358x; 1.0358x over previous
//
#include <hip/hip_runtime.h>
#include <hip/hip_bf16.h>
#include <cstdint>
#include <cstddef>

typedef __attribute__((ext_vector_type(8))) short bf16x8;
typedef __attribute__((ext_vector_type(8))) unsigned short ushort8;
typedef __attribute__((ext_vector_type(4))) unsigned short ushort4v;
typedef __attribute__((ext_vector_type(4))) float f32x4;

#define B_ 8
#define S_ 1024
#define E_ 1024
#define H_ 16
#define D_ 64
#define NW_ (S_ / 64)  // mask words per row

__device__ __forceinline__ unsigned short f2bf(float f) {
    union { float fp; unsigned int u; } v; v.fp = f;
    unsigned int u = v.u;
    return (unsigned short)((u + 0x7fffu + ((u >> 16) & 1u)) >> 16);
}

__device__ __forceinline__ float fexp2(float x) {
    return __builtin_amdgcn_exp2f(x);  // v_exp_f32: D = 2^S0
}

__device__ __forceinline__ unsigned cvt_pk_bf16(float lo, float hi) {
    unsigned r;
    asm("v_cvt_pk_bf16_f32 %0, %1, %2" : "=v"(r) : "v"(lo), "v"(hi));
    return r;
}

__device__ __forceinline__ void gload16(const void* g, void* l) {
    __builtin_amdgcn_global_load_lds((__attribute__((address_space(1))) void*)g,
                                     (__attribute__((address_space(3))) void*)l,
                                     16, 0, 0);
}

// ---------------- f32 -> bf16 bulk convert ----------------------------------
__global__ __launch_bounds__(256) void f32_to_bf16(const float* __restrict__ in,
                                                   unsigned short* __restrict__ out,
                                                   int n8) {
    int i = blockIdx.x * 256 + threadIdx.x;
    const int stride = gridDim.x * 256;
    for (; i < n8; i += stride) {
        float4 f0 = ((const float4*)in)[i * 2];
        float4 f1 = ((const float4*)in)[i * 2 + 1];
        union { unsigned u[4]; ushort8 v; } o;
        o.u[0] = cvt_pk_bf16(f0.x, f0.y);
        o.u[1] = cvt_pk_bf16(f0.z, f0.w);
        o.u[2] = cvt_pk_bf16(f1.x, f1.y);
        o.u[3] = cvt_pk_bf16(f1.z, f1.w);
        ((ushort8*)out)[i] = o.v;
    }
}

// ---------------- weight transpose-convert: 4 × (W[K][N] f32 -> Wt[N][K]) ---
__global__ __launch_bounds__(256) void wtrans4(const float* __restrict__ W0,
                                               const float* __restrict__ W1,
                                               const float* __restrict__ W2,
                                               const float* __restrict__ W3,
                                               unsigned short* __restrict__ T0,
                                               unsigned short* __restrict__ T1,
                                               unsigned short* __restrict__ T2,
                                               unsigned short* __restrict__ T3) {
    const float* W = (blockIdx.z == 0) ? W0 : (blockIdx.z == 1) ? W1 : (blockIdx.z == 2) ? W2 : W3;
    unsigned short* Wt = (blockIdx.z == 0) ? T0 : (blockIdx.z == 1) ? T1 : (blockIdx.z == 2) ? T2 : T3;
    __shared__ float tile[32][33];
    const int k0 = blockIdx.y * 32, n0 = blockIdx.x * 32;
    const int tx = threadIdx.x & 31, ty = threadIdx.x >> 5;
#pragma unroll
    for (int i = ty; i < 32; i += 8)
        tile[i][tx] = W[(size_t)(k0 + i) * E_ + n0 + tx];
    __syncthreads();
#pragma unroll
    for (int i = ty; i < 32; i += 8)
        Wt[(size_t)(n0 + i) * E_ + k0 + tx] = f2bf(tile[tx][i]);
}

// ---------------- mask bit-pack with inline dtype detection -----------------
// Each block scans the first 4KB of the mask itself: packed bool bytes read
// as u32 exceed 1 with overwhelming probability; int32 0/1 values never do.
__global__ __launch_bounds__(256) void pack_mask(const void* __restrict__ maskp,
                                                 unsigned long long* __restrict__ mbits) {
    const unsigned int* m32h = (const unsigned int*)maskp;
    unsigned int bad = 0;
    for (int i = threadIdx.x; i < 4096; i += 256) bad |= (m32h[i] > 1u) ? 1u : 0u;
    __shared__ int s_is32;
    if (threadIdx.x == 0) s_is32 = 1;
    __syncthreads();
    if (bad) s_is32 = 0;
    __syncthreads();
    const int mask32 = s_is32;

    const int lane = threadIdx.x & 63;
    const int gw = blockIdx.x * 4 + (threadIdx.x >> 6);
    const int nwaves = gridDim.x * 4;
    const int totw = B_ * S_ * NW_;
    for (int w = gw; w < totw; w += nwaves) {
        bool m;
        if (mask32) m = ((const int*)maskp)[(size_t)w * 64 + lane] != 0;
        else        m = ((const unsigned char*)maskp)[(size_t)w * 64 + lane] != 0;
        unsigned long long bits = __ballot(m);
        if (lane == 0) mbits[w] = bits;
    }
}

// ---------------- GEMM (BK=64 + rule-21 swizzle, single buffer) -------------
// LDS [128][64] bf16. Staging: inverse-swizzled GLOBAL source chunk
// (col_chunk = (l&7)^(l>>3)) + linear global_load_lds dest; reads use
// slot = (kk*4+l4)^(row&7)  ->  2-way bank aliasing (free).
// EPI 0: bf16 [B,H,S,D] (scaled); EPI 2: bf16 [B,H,D,S]; EPI 3: f32+resid.
template <int EPI>
__global__ __launch_bounds__(256) void gemm_bt(const unsigned short* __restrict__ A,
                                               const unsigned short* __restrict__ Bt,
                                               void* __restrict__ Cp,
                                               const float* __restrict__ resid,
                                               float cscale) {
    __shared__ unsigned short As[128 * 64];  // 16 KB
    __shared__ unsigned short Bs[128 * 64];  // 16 KB
    const int t = threadIdx.x;
    const int lane = t & 63, w = t >> 6;
    const int wr = w >> 1, wc = w & 1;
    const int l15 = lane & 15, l4 = lane >> 4;
    const int m0 = blockIdx.x * 128, n0 = blockIdx.y * 128;

    const int lr = lane >> 3, lc = lane & 7;
    const int csrc = (lc ^ lr) * 8;  // inverse-swizzled source col (shorts)
    const unsigned short* Ag[4];
    const unsigned short* Bg[4];
#pragma unroll
    for (int g = 0; g < 4; ++g) {
        Ag[g] = A + (size_t)(m0 + w * 32 + g * 8 + lr) * E_ + csrc;
        Bg[g] = Bt + (size_t)(n0 + w * 32 + g * 8 + lr) * E_ + csrc;
    }
    unsigned short* Al = &As[w * 32 * 64];
    unsigned short* Bl = &Bs[w * 32 * 64];

    f32x4 acc[4][4];
#pragma unroll
    for (int i = 0; i < 4; ++i)
#pragma unroll
        for (int j = 0; j < 4; ++j) acc[i][j] = (f32x4){0.f, 0.f, 0.f, 0.f};

    const int r7 = (l15 & 7) << 4;  // (row&7)*16 bytes
    const char* AsB = (const char*)As;
    const char* BsB = (const char*)Bs;

    for (int kt = 0; kt < E_; kt += 64) {
#pragma unroll
        for (int g = 0; g < 4; ++g) {
            gload16(Ag[g] + kt, Al + g * 512);
            gload16(Bg[g] + kt, Bl + g * 512);
        }
        __syncthreads();
#pragma unroll
        for (int kk = 0; kk < 2; ++kk) {
            bf16x8 af[4], bfv[4];
#pragma unroll
            for (int mi = 0; mi < 4; ++mi)
                af[mi] = *(const bf16x8*)(AsB + (size_t)(wr * 64 + mi * 16 + l15) * 128 +
                                          ((((kk * 4 + l4) << 4)) ^ r7));
#pragma unroll
            for (int ni = 0; ni < 4; ++ni)
                bfv[ni] = *(const bf16x8*)(BsB + (size_t)(wc * 64 + ni * 16 + l15) * 128 +
                                           ((((kk * 4 + l4) << 4)) ^ r7));
#pragma unroll
            for (int mi = 0; mi < 4; ++mi)
#pragma unroll
                for (int ni = 0; ni < 4; ++ni)
                    acc[mi][ni] = __builtin_amdgcn_mfma_f32_16x16x32_bf16(af[mi], bfv[ni],
                                                                          acc[mi][ni], 0, 0, 0);
        }
        __syncthreads();
    }
#pragma unroll
    for (int mi = 0; mi < 4; ++mi) {
#pragma unroll
        for (int ni = 0; ni < 4; ++ni) {
#pragma unroll
            for (int r = 0; r < 4; ++r) {
                const int m = m0 + wr * 64 + mi * 16 + l4 * 4 + r;
                const int n = n0 + wc * 64 + ni * 16 + l15;
                const float v = acc[mi][ni][r];
                if (EPI == 0) {
                    const int b = m >> 10, s = m & 1023, h = n >> 6, d = n & 63;
                    ((unsigned short*)Cp)[(((size_t)b * H_ + h) * S_ + s) * D_ + d] = f2bf(v * cscale);
                } else if (EPI == 2) {
                    const int b = m >> 10, s = m & 1023, h = n >> 6, d = n & 63;
                    ((unsigned short*)Cp)[(((size_t)b * H_ + h) * D_ + d) * S_ + s] = f2bf(v);
                } else {
                    const size_t idx = (size_t)m * E_ + n;
                    ((float*)Cp)[idx] = v + resid[idx];
                }
            }
        }
    }
}

// ---------------- flash attention (8 waves, dbuf K/V via global_load_lds) ---
// 1D grid 1024, bijective XCD swizzle. 8 waves; wave w owns q rows q0+w*16.
// 2-phase pipeline: ONE barrier/tile; tile t+1's K/V staged by global_load_lds
// (pre-swizzled source, linear dest) right after the barrier -> loads fly
// across the whole QK+softmax+PV phase. LDS 48KB: 2x(8+8) K/V + 16 P.
// Q pre-scaled by 0.125*log2(e); exp2 domain; defer-max THR=8.
__global__ __launch_bounds__(512) void attn_kernel(const unsigned short* __restrict__ Qh,
                                                   const unsigned short* __restrict__ Kh,
                                                   const unsigned short* __restrict__ Vt,
                                                   const unsigned long long* __restrict__ mbits,
                                                   unsigned short* __restrict__ degree) {
    __shared__ unsigned short Ks[2][64 * 64];   // 16 KB
    __shared__ unsigned short Vs[2][64 * 64];   // 16 KB
    __shared__ unsigned short Ps[8 * 16 * 64];  // 16 KB (per-wave 16x64)
    const int t = threadIdx.x;
    const int lane = t & 63, w = t >> 6;  // w 0..7
    const int l15 = lane & 15, l4 = lane >> 4;
    const int i = blockIdx.x;
    const int L = (i & 7) * 128 + (i >> 3);  // bijective, nwg=1024
    const int bh = L >> 3, b = bh >> 4, h = bh & 15;
    const int q0 = (L & 7) * 128;
    const int myq = q0 + w * 16 + l15;

    const unsigned long long* mrow = mbits + ((size_t)b * S_ + myq) * NW_;

    bf16x8 qf[2];
    {
        const unsigned short* qptr = Qh + ((size_t)bh * S_ + myq) * D_ + l4 * 8;
        qf[0] = *(const bf16x8*)qptr;
        qf[1] = *(const bf16x8*)(qptr + 32);
    }
    f32x4 O[4];
#pragma unroll
    for (int idx = 0; idx < 4; ++idx) O[idx] = (f32x4){0.f, 0.f, 0.f, 0.f};
    float mrun = -3e38f, lrun = 0.f;

    // staging: 512 lanes x (1 K-chunk + 1 V-chunk) of 16B per tile.
    // row = t>>3, slot = t&7; SOURCE chunk = slot ^ (row&7) (rule-21 inverse
    // swizzle); LDS dest linear (wave-uniform base + lane*16).
    const int srow = t >> 3, slot = t & 7;
    const int scs = (slot ^ (srow & 7)) * 8;  // source col in shorts
    const unsigned short* kgb = Kh + ((size_t)bh * S_ + srow) * D_ + scs;
    const unsigned short* vgb = Vt + ((size_t)bh * D_ + srow) * S_ + scs;

    char* PsB = (char*)Ps + w * 2048;
    const int psw = (l15 & 7) << 4;

    // prologue: stage tile 0 into buffer 0
    gload16(kgb, &Ks[0][w * 512]);
    gload16(vgb, &Vs[0][w * 512]);

    int cur = 0;
    for (int jt = 0; jt < S_; jt += 64) {
        __syncthreads();  // drains DMA for buf[cur]; closes prev reads of buf[cur^1]
        if (jt + 64 < S_) {
            gload16(kgb + (size_t)(jt + 64) * D_, &Ks[cur ^ 1][w * 512]);
            gload16(vgb + (jt + 64), &Vs[cur ^ 1][w * 512]);
        }
        const unsigned long long mw = mrow[jt >> 6];
        const char* KsB = (const char*)Ks[cur];
        const char* VsB = (const char*)Vs[cur];

        // S^T = mfma(K, Q): lane holds S[q=l15][k = ni*16 + l4*4 + r]
        f32x4 sacc[4];
#pragma unroll
        for (int idx = 0; idx < 4; ++idx) sacc[idx] = (f32x4){0.f, 0.f, 0.f, 0.f};
#pragma unroll
        for (int ni = 0; ni < 4; ++ni) {
            const int row = l15 + ni * 16;
            const int sw = (row & 7) << 4;
            bf16x8 b0 = *(const bf16x8*)(KsB + row * 128 + ((l4 * 16) ^ sw));
            bf16x8 b1 = *(const bf16x8*)(KsB + row * 128 + ((64 + l4 * 16) ^ sw));
            sacc[ni] = __builtin_amdgcn_mfma_f32_16x16x32_bf16(b0, qf[0], sacc[ni], 0, 0, 0);
            sacc[ni] = __builtin_amdgcn_mfma_f32_16x16x32_bf16(b1, qf[1], sacc[ni], 0, 0, 0);
        }

        // mask + in-lane row max (16 values) + 2-step cross-group reduce
        float m0 = -3e38f;
#pragma unroll
        for (int ni = 0; ni < 4; ++ni) {
#pragma unroll
            for (int r = 0; r < 4; ++r) {
                const int k = ni * 16 + l4 * 4 + r;
                const float s = ((mw >> k) & 1ull) ? -1e9f : sacc[ni][r];
                sacc[ni][r] = s;
                m0 = fmaxf(m0, s);
            }
        }
        m0 = fmaxf(m0, __shfl_xor(m0, 16, 64));
        m0 = fmaxf(m0, __shfl_xor(m0, 32, 64));
        // defer-max: only rescale when some lane's max grew past threshold
        if (!__all(m0 <= mrun + 8.f)) {
            const float mnew = fmaxf(mrun, m0);
            const float corr = fexp2(mrun - mnew);
            lrun *= corr;
#pragma unroll
            for (int df = 0; df < 4; ++df)
#pragma unroll
                for (int r = 0; r < 4; ++r) O[df][r] *= corr;
            mrun = mnew;
        }
        // exp + in-lane sum + P pack (cvt_pk) + write (4 x ds_write_b64)
        float ps = 0.f;
#pragma unroll
        for (int ni = 0; ni < 4; ++ni) {
            float p0 = fexp2(sacc[ni][0] - mrun);
            float p1 = fexp2(sacc[ni][1] - mrun);
            float p2 = fexp2(sacc[ni][2] - mrun);
            float p3 = fexp2(sacc[ni][3] - mrun);
            ps += (p0 + p1) + (p2 + p3);
            uint2 pw;
            pw.x = cvt_pk_bf16(p0, p1);
            pw.y = cvt_pk_bf16(p2, p3);
            *(uint2*)(PsB + l15 * 128 + ((ni * 32 + l4 * 8) ^ psw)) = pw;
        }
        ps += __shfl_xor(ps, 16, 64);
        ps += __shfl_xor(ps, 32, 64);
        lrun += ps;

        asm volatile("s_waitcnt lgkmcnt(0)" ::: "memory");
        bf16x8 pa0 = *(const bf16x8*)(PsB + l15 * 128 + ((l4 * 16) ^ psw));
        bf16x8 pa1 = *(const bf16x8*)(PsB + l15 * 128 + ((64 + l4 * 16) ^ psw));
        // O^T = mfma(V, P): col = q = l15, row = d
#pragma unroll
        for (int df = 0; df < 4; ++df) {
            const int row = l15 + df * 16;
            const int sw = (row & 7) << 4;
            bf16x8 v0 = *(const bf16x8*)(VsB + row * 128 + ((l4 * 16) ^ sw));
            bf16x8 v1 = *(const bf16x8*)(VsB + row * 128 + ((64 + l4 * 16) ^ sw));
            O[df] = __builtin_amdgcn_mfma_f32_16x16x32_bf16(v0, pa0, O[df], 0, 0, 0);
            O[df] = __builtin_amdgcn_mfma_f32_16x16x32_bf16(v1, pa1, O[df], 0, 0, 0);
        }
        cur ^= 1;
    }

    const float inv = 1.f / lrun;
#pragma unroll
    for (int df = 0; df < 4; ++df) {
        ushort4v ow;
#pragma unroll
        for (int r = 0; r < 4; ++r) ow[r] = f2bf(O[df][r] * inv);
        const size_t dst = ((size_t)b * S_ + myq) * (size_t)(H_ * D_) +
                           h * 64 + df * 16 + l4 * 4;
        *(ushort4v*)(degree + dst) = ow;
    }
}

// ---------------- in-place row LayerNorm over E=1024 ------------------------
__global__ __launch_bounds__(256) void lnorm(float* __restrict__ io,
                                             const float* __restrict__ gamma,
                                             const float* __restrict__ beta) {
    const int row = blockIdx.x;
    const int t = threadIdx.x;
    float4 v = ((const float4*)(io + (size_t)row * E_))[t];
    float s = v.x + v.y + v.z + v.w;
    float q = v.x * v.x + v.y * v.y + v.z * v.z + v.w * v.w;
#pragma unroll
    for (int off = 32; off; off >>= 1) {
        s += __shfl_down(s, off, 64);
        q += __shfl_down(q, off, 64);
    }
    __shared__ float red[8];
    const int wid = t >> 6;
    if ((t & 63) == 0) { red[wid] = s; red[4 + wid] = q; }
    __syncthreads();
    const float ts = red[0] + red[1] + red[2] + red[3];
    const float tq = red[4] + red[5] + red[6] + red[7];
    const float mean = ts * (1.0f / E_);
    const float var = tq * (1.0f / E_) - mean * mean;
    const float rstd = rsqrtf(var + 1e-5f);
    const float4 g = ((const float4*)gamma)[t];
    const float4 bb = ((const float4*)beta)[t];
    v.x = (v.x - mean) * rstd * g.x + bb.x;
    v.y = (v.y - mean) * rstd * g.y + bb.y;
    v.z = (v.z - mean) * rstd * g.z + bb.z;
    v.w = (v.w - mean) * rstd * g.w + bb.w;
    ((float4*)(io + (size_t)row * E_))[t] = v;
}

extern "C" void kernel_launch(void* const* d_in, const int* in_sizes, int n_in,
                              void* d_out, int out_size, void* d_ws, size_t ws_size,
                              hipStream_t stream) {
    const float* query = (const float*)d_in[0];
    const float* key_ = (const float*)d_in[1];
    const float* value = (const float*)d_in[2];
    const void* maskp = d_in[3];
    const float* Wq = (const float*)d_in[4];
    const float* Wk = (const float*)d_in[5];
    const float* Wv = (const float*)d_in[6];
    const float* Wo = (const float*)d_in[7];
    const float* gamma = (const float*)d_in[8];
    const float* beta = (const float*)d_in[9];
    float* out = (float*)d_out;
    char* ws = (char*)d_ws;
    const size_t MB = 1024ull * 1024ull;

    unsigned short* WqT = (unsigned short*)(ws + 0 * MB);
    unsigned short* WkT = (unsigned short*)(ws + 2 * MB);
    unsigned short* WvT = (unsigned short*)(ws + 4 * MB);
    unsigned short* WoT = (unsigned short*)(ws + 6 * MB);
    unsigned short* Qh = (unsigned short*)(ws + 8 * MB);   // [B,H,S,D] bf16
    unsigned short* Kh = (unsigned short*)(ws + 24 * MB);  // [B,H,S,D] bf16
    unsigned short* Vt = (unsigned short*)(ws + 40 * MB);  // [B,H,D,S] bf16
    unsigned short* deg = (unsigned short*)(ws + 56 * MB); // [B,S,H*D] bf16
    unsigned short* Abf = deg;  // bf16 A staging; dead once attn writes deg
    unsigned long long* mbits = (unsigned long long*)(ws + 72 * MB + 4096);

    const int n8 = B_ * S_ * E_ / 8;
    const float qscale = 0.125f * 1.4426950408889634f;  // 1/sqrt(D) * log2(e)

    wtrans4<<<dim3(32, 32, 4), 256, 0, stream>>>(Wq, Wk, Wv, Wo, WqT, WkT, WvT, WoT);
    pack_mask<<<2048, 256, 0, stream>>>(maskp, mbits);

    f32_to_bf16<<<2048, 256, 0, stream>>>(query, Abf, n8);
    gemm_bt<0><<<dim3(64, 8), 256, 0, stream>>>(Abf, WqT, Qh, nullptr, qscale);
    f32_to_bf16<<<2048, 256, 0, stream>>>(key_, Abf, n8);
    gemm_bt<0><<<dim3(64, 8), 256, 0, stream>>>(Abf, WkT, Kh, nullptr, 1.0f);
    f32_to_bf16<<<2048, 256, 0, stream>>>(value, Abf, n8);
    gemm_bt<2><<<dim3(64, 8), 256, 0, stream>>>(Abf, WvT, Vt, nullptr, 1.0f);

    attn_kernel<<<1024, 512, 0, stream>>>(Qh, Kh, Vt, mbits, deg);

    gemm_bt<3><<<dim3(64, 8), 256, 0, stream>>>(deg, WoT, out, query, 1.0f);
    lnorm<<<8192, 256, 0, stream>>>(out, gamma, beta);
}